// Round 1
// baseline (321.662 us; speedup 1.0000x reference)
//
#include <hip/hip_runtime.h>
#include <math.h>

// Retinal_NET: only t=59 of the output survives ([:, -1]), so only
// x[:, :, 31:60] is ever needed (causal 15-tap temporal convs, twice).
// Both 5x5 convs are stride-5 => non-overlapping partitions.
//
// Pipeline:
//   k_space:         s1[b][ti][50][50], ti=0..28 <-> tau=31..59   (ws)
//   k_temporal_last: first = relu(15-tap temporal conv of s1); then 5x5/5
//                    conv -> flat[b][tp][100], tp=0..14 <-> t=45..59 (ws)
//   k_head:          ama/gang sigmoid head at t=59 -> out[16]

#define X_T   60
#define X_HW  250
#define S1_T0 31
#define S1_NT 29
#define NT    15

__global__ __launch_bounds__(256) void k_space(const float* __restrict__ x,
                                               const float* __restrict__ sw,
                                               float* __restrict__ s1) {
    int pix = blockIdx.x * 256 + threadIdx.x;   // 0..2499 over 50x50
    if (pix >= 2500) return;
    int ti = blockIdx.y;   // 0..28
    int b  = blockIdx.z;   // 0..15
    int h = pix / 50;
    int w = pix - h * 50;
    const float* xp = x + (size_t)b * (X_T * X_HW * X_HW)
                        + (size_t)(S1_T0 + ti) * (X_HW * X_HW)
                        + (size_t)(h * 5) * X_HW + (size_t)(w * 5);
    float wr[25];
#pragma unroll
    for (int i = 0; i < 25; ++i) wr[i] = sw[i];
    float acc = 0.f;
#pragma unroll
    for (int dh = 0; dh < 5; ++dh) {
        const float* row = xp + dh * X_HW;
#pragma unroll
        for (int dw = 0; dw < 5; ++dw) acc = fmaf(wr[dh * 5 + dw], row[dw], acc);
    }
    s1[((size_t)b * S1_NT + ti) * 2500 + pix] = acc;
}

__global__ __launch_bounds__(256) void k_temporal_last(const float* __restrict__ s1,
                                                       const float* __restrict__ tw,
                                                       const float* __restrict__ lw,
                                                       float* __restrict__ flat) {
    int tp = blockIdx.x;   // 0..14  (t = 45 + tp)
    int b  = blockIdx.y;   // 0..15
    __shared__ float firstL[2500];
    __shared__ float twL[15];
    __shared__ float lwL[25];
    int tid = threadIdx.x;
    if (tid < 15) twL[tid] = tw[tid];
    if (tid < 25) lwL[tid] = lw[tid];
    __syncthreads();
    // first[t=45+tp][pix] = relu( sum_k tw[k] * s1[tau_i = tp+k][pix] )
    const float* s1b = s1 + ((size_t)b * S1_NT + tp) * 2500;
    for (int pix = tid; pix < 2500; pix += 256) {
        float acc = 0.f;
#pragma unroll
        for (int k = 0; k < 15; ++k) acc = fmaf(twL[k], s1b[(size_t)k * 2500 + pix], acc);
        firstL[pix] = fmaxf(acc, 0.f);
    }
    __syncthreads();
    // out[t][ph][pw] = sum_{dh,dw} lw[dh*5+dw] * first[t][ph*5+dh][pw*5+dw]
    if (tid < 100) {
        int ph = tid / 10;
        int pw = tid - ph * 10;
        float acc = 0.f;
#pragma unroll
        for (int dh = 0; dh < 5; ++dh)
#pragma unroll
            for (int dw = 0; dw < 5; ++dw)
                acc = fmaf(lwL[dh * 5 + dw], firstL[(ph * 5 + dh) * 50 + pw * 5 + dw], acc);
        flat[((size_t)b * NT + tp) * 100 + tid] = acc;
    }
}

__global__ __launch_bounds__(64) void k_head(const float* __restrict__ flat,
                                             const float* __restrict__ ca_p,
                                             const float* __restrict__ ak,
                                             const float* __restrict__ ab_p,
                                             const float* __restrict__ alpha_p,
                                             const float* __restrict__ cg_p,
                                             const float* __restrict__ gk,
                                             const float* __restrict__ gb_p,
                                             const float* __restrict__ colw,
                                             float* __restrict__ out) {
    int b = blockIdx.x;   // 0..15
    int j = threadIdx.x;  // 0..63, active j<49
    const float* fb = flat + (size_t)b * NT * 100;
    float val = 0.f;
    if (j < 49) {
        float ca = ca_p[0], ab = ab_p[0], alpha = alpha_p[0];
        float cg = cg_p[0], gb = gb_p[0];
        int ia = 2 * j;                 // ama_pre index -> flat[2j]
        int ig = (2 * j + 25) % 100;    // gang (roll -25) -> flat[(2j+25)%100]
        float a = ab;
        float g = gb;
#pragma unroll
        for (int k = 0; k < 15; ++k) {  // t = 45+k, causal taps at d=59
            a = fmaf(ak[k], ca * fb[k * 100 + ia], a);
            g = fmaf(gk[k], cg * fb[k * 100 + ig], g);
        }
        float asig = 1.f / (1.f + expf(-a));
        float ama  = alpha * asig;
        float gt   = 1.f / (1.f + expf(-(g - fabsf(ama))));
        val = colw[j] * gt;
    }
#pragma unroll
    for (int off = 32; off > 0; off >>= 1) val += __shfl_down(val, off);
    if (j == 0) out[b] = val;
}

extern "C" void kernel_launch(void* const* d_in, const int* in_sizes, int n_in,
                              void* d_out, int out_size, void* d_ws, size_t ws_size,
                              hipStream_t stream) {
    const float* x    = (const float*)d_in[0];
    const float* sw   = (const float*)d_in[1];   // space_w   (1,1,1,5,5)
    const float* tw   = (const float*)d_in[2];   // temporal_w(1,1,15,1,1)
    const float* lw   = (const float*)d_in[3];   // last_w    (1,1,1,5,5)
    const float* ca   = (const float*)d_in[4];   // ama_create_w (scalar)
    const float* ak   = (const float*)d_in[5];   // ama_kernel_w (15)
    const float* akb  = (const float*)d_in[6];   // ama_kernel_b (1)
    const float* aal  = (const float*)d_in[7];   // ama_alpha_w  (scalar)
    const float* gc   = (const float*)d_in[8];   // gang_create_w (scalar)
    const float* gk   = (const float*)d_in[9];   // gang_kernel_w (15)
    const float* gkb  = (const float*)d_in[10];  // gang_kernel_b (1)
    const float* gcol = (const float*)d_in[11];  // gang_col_w (49)

    float* s1   = (float*)d_ws;                       // 16*29*2500 floats = 4.64 MB
    float* flat = s1 + (size_t)16 * S1_NT * 2500;     // 16*15*100 floats

    k_space<<<dim3(10, S1_NT, 16), 256, 0, stream>>>(x, sw, s1);
    k_temporal_last<<<dim3(NT, 16), 256, 0, stream>>>(s1, tw, lw, flat);
    k_head<<<dim3(16), 64, 0, stream>>>(flat, ca, ak, akb, aal, gc, gk, gkb, gcol,
                                        (float*)d_out);
}

// Round 2
// 320.353 us; speedup vs baseline: 1.0041x; 1.0041x over previous
//
#include <hip/hip_runtime.h>
#include <math.h>

// Retinal_NET: only t=59 of the output survives ([:, -1]), so only
// x[:, :, 31:60] is ever needed (causal 15-tap temporal convs, twice).
// Both 5x5 convs are stride-5 => non-overlapping partitions.
//
// Pipeline:
//   k_space:         s1[b][ti][50][50], ti=0..28 <-> tau=31..59   (ws)
//                    2 outputs/thread, float2 loads (all 8B-aligned)
//   k_temporal_last: first = relu(15-tap temporal conv of s1); then 5x5/5
//                    conv -> flat[b][tp][100], tp=0..14 <-> t=45..59 (ws)
//   k_head:          ama/gang sigmoid head at t=59 -> out[16]

#define X_T     60
#define X_FRAME 62500     // 250*250
#define X_BATCH 3750000   // 60*62500
#define S1_T0   31
#define S1_NT   29
#define NT      15

__global__ __launch_bounds__(256) void k_space(const float* __restrict__ x,
                                               const float* __restrict__ sw,
                                               float* __restrict__ s1) {
    int idx = blockIdx.x * 256 + threadIdx.x;   // 0..1249 over 50 rows x 25 col-pairs
    if (idx >= 1250) return;
    int ti = blockIdx.y;   // 0..28
    int b  = blockIdx.z;   // 0..15
    int h  = idx / 25;
    int wp = idx - h * 25;     // col-pair: outputs w=2*wp, 2*wp+1
    const float* xp = x + (size_t)b * X_BATCH
                        + (size_t)(S1_T0 + ti) * X_FRAME
                        + (size_t)(h * 5) * 250 + (size_t)(wp * 10);
    float wr[25];
#pragma unroll
    for (int i = 0; i < 25; ++i) wr[i] = sw[i];
    float acc0 = 0.f, acc1 = 0.f;
#pragma unroll
    for (int dh = 0; dh < 5; ++dh) {
        const float2* r2 = (const float2*)(xp + dh * 250);  // 8B-aligned
        float f[10];
#pragma unroll
        for (int q = 0; q < 5; ++q) {
            float2 v = r2[q];
            f[2 * q] = v.x;
            f[2 * q + 1] = v.y;
        }
#pragma unroll
        for (int dw = 0; dw < 5; ++dw) {
            acc0 = fmaf(wr[dh * 5 + dw], f[dw], acc0);
            acc1 = fmaf(wr[dh * 5 + dw], f[dw + 5], acc1);
        }
    }
    float2* o2 = (float2*)(s1 + ((size_t)b * S1_NT + ti) * 2500);
    o2[h * 25 + wp] = make_float2(acc0, acc1);
}

__global__ __launch_bounds__(256) void k_temporal_last(const float* __restrict__ s1,
                                                       const float* __restrict__ tw,
                                                       const float* __restrict__ lw,
                                                       float* __restrict__ flat) {
    int tp = blockIdx.x;   // 0..14  (t = 45 + tp)
    int b  = blockIdx.y;   // 0..15
    __shared__ float firstL[2500];
    __shared__ float twL[15];
    __shared__ float lwL[25];
    int tid = threadIdx.x;
    if (tid < 15) twL[tid] = tw[tid];
    if (tid < 25) lwL[tid] = lw[tid];
    __syncthreads();
    // first[t=45+tp][pix] = relu( sum_k tw[k] * s1[tau_i = tp+k][pix] )
    const float2* s1b2 = (const float2*)(s1 + ((size_t)b * S1_NT + tp) * 2500);
    float2* firstL2 = (float2*)firstL;
    for (int p2 = tid; p2 < 1250; p2 += 256) {
        float ax = 0.f, ay = 0.f;
#pragma unroll
        for (int k = 0; k < 15; ++k) {
            float2 v = s1b2[(size_t)k * 1250 + p2];
            ax = fmaf(twL[k], v.x, ax);
            ay = fmaf(twL[k], v.y, ay);
        }
        firstL2[p2] = make_float2(fmaxf(ax, 0.f), fmaxf(ay, 0.f));
    }
    __syncthreads();
    // out[t][ph][pw] = sum_{dh,dw} lw[dh*5+dw] * first[t][ph*5+dh][pw*5+dw]
    if (tid < 100) {
        int ph = tid / 10;
        int pw = tid - ph * 10;
        float acc = 0.f;
#pragma unroll
        for (int dh = 0; dh < 5; ++dh)
#pragma unroll
            for (int dw = 0; dw < 5; ++dw)
                acc = fmaf(lwL[dh * 5 + dw], firstL[(ph * 5 + dh) * 50 + pw * 5 + dw], acc);
        flat[((size_t)b * NT + tp) * 100 + tid] = acc;
    }
}

__global__ __launch_bounds__(64) void k_head(const float* __restrict__ flat,
                                             const float* __restrict__ ca_p,
                                             const float* __restrict__ ak,
                                             const float* __restrict__ ab_p,
                                             const float* __restrict__ alpha_p,
                                             const float* __restrict__ cg_p,
                                             const float* __restrict__ gk,
                                             const float* __restrict__ gb_p,
                                             const float* __restrict__ colw,
                                             float* __restrict__ out) {
    int b = blockIdx.x;   // 0..15
    int j = threadIdx.x;  // 0..63, active j<49
    const float* fb = flat + (size_t)b * NT * 100;
    float val = 0.f;
    if (j < 49) {
        float ca = ca_p[0], ab = ab_p[0], alpha = alpha_p[0];
        float cg = cg_p[0], gb = gb_p[0];
        int ia = 2 * j;                 // ama_pre index -> flat[2j]
        int ig = (2 * j + 25) % 100;    // gang (roll -25) -> flat[(2j+25)%100]
        float a = ab;
        float g = gb;
#pragma unroll
        for (int k = 0; k < 15; ++k) {  // t = 45+k, causal taps at d=59
            a = fmaf(ak[k], ca * fb[k * 100 + ia], a);
            g = fmaf(gk[k], cg * fb[k * 100 + ig], g);
        }
        float asig = 1.f / (1.f + expf(-a));
        float ama  = alpha * asig;
        float gt   = 1.f / (1.f + expf(-(g - fabsf(ama))));
        val = colw[j] * gt;
    }
#pragma unroll
    for (int off = 32; off > 0; off >>= 1) val += __shfl_down(val, off);
    if (j == 0) out[b] = val;
}

extern "C" void kernel_launch(void* const* d_in, const int* in_sizes, int n_in,
                              void* d_out, int out_size, void* d_ws, size_t ws_size,
                              hipStream_t stream) {
    const float* x    = (const float*)d_in[0];
    const float* sw   = (const float*)d_in[1];   // space_w   (1,1,1,5,5)
    const float* tw   = (const float*)d_in[2];   // temporal_w(1,1,15,1,1)
    const float* lw   = (const float*)d_in[3];   // last_w    (1,1,1,5,5)
    const float* ca   = (const float*)d_in[4];   // ama_create_w (scalar)
    const float* ak   = (const float*)d_in[5];   // ama_kernel_w (15)
    const float* akb  = (const float*)d_in[6];   // ama_kernel_b (1)
    const float* aal  = (const float*)d_in[7];   // ama_alpha_w  (scalar)
    const float* gc   = (const float*)d_in[8];   // gang_create_w (scalar)
    const float* gk   = (const float*)d_in[9];   // gang_kernel_w (15)
    const float* gkb  = (const float*)d_in[10];  // gang_kernel_b (1)
    const float* gcol = (const float*)d_in[11];  // gang_col_w (49)

    float* s1   = (float*)d_ws;                       // 16*29*2500 floats = 4.64 MB
    float* flat = s1 + (size_t)16 * S1_NT * 2500;     // 16*15*100 floats

    k_space<<<dim3(5, S1_NT, 16), 256, 0, stream>>>(x, sw, s1);
    k_temporal_last<<<dim3(NT, 16), 256, 0, stream>>>(s1, tw, lw, flat);
    k_head<<<dim3(16), 64, 0, stream>>>(flat, ca, ak, akb, aal, gc, gk, gkb, gcol,
                                        (float*)d_out);
}